// Round 9
// baseline (341.754 us; speedup 1.0000x reference)
//
#include <hip/hip_runtime.h>
#include <math.h>

namespace {

constexpr int   B_ = 2;
constexpr int   N_ = 16384;
constexpr int   M_ = 2048;
constexpr int   D_ = 256;
constexpr float QS_ = 0.09016844005556021f;  // (1/sqrt(256)) * log2(e), folded into Wq/bq
constexpr float LN_EPS_ = 1e-5f;
constexpr int   NS_  = 16;                   // n-splits in attn_out
constexpr int   NPB_ = N_ / NS_;             // 1024 n per block
constexpr int   NCOPY_ = 16;                 // one part copy per ns -> plain stores
constexpr int   NT16_ = N_ / 16;             // 1024 n16-groups per batch
constexpr int   MT32_ = M_ / 32;             // 64 m-tiles per batch
constexpr size_t OUTSZ_ = (size_t)B_*M_*D_;

typedef _Float16 f16x8 __attribute__((ext_vector_type(8)));
typedef float    f32x16 __attribute__((ext_vector_type(16)));
typedef unsigned int u32x2 __attribute__((ext_vector_type(2)));
typedef unsigned int u32x4 __attribute__((ext_vector_type(4)));   // native vec for nontemporal

__device__ inline f16x8 as_h8(uint4 u) { return __builtin_bit_cast(f16x8, u); }
__device__ inline unsigned short f16bits(float x) {
    return __builtin_bit_cast(unsigned short, (_Float16)x);
}
__device__ inline uint4 pack8(const unsigned short v[8]) {
    return make_uint4((uint32_t)v[0] | ((uint32_t)v[1] << 16),
                      (uint32_t)v[2] | ((uint32_t)v[3] << 16),
                      (uint32_t)v[4] | ((uint32_t)v[5] << 16),
                      (uint32_t)v[6] | ((uint32_t)v[7] << 16));
}
__device__ inline void nt_store4(unsigned int a, unsigned int b,
                                 unsigned int c, unsigned int d, uint4* dst) {
    u32x4 v; v[0] = a; v[1] = b; v[2] = c; v[3] = d;
    __builtin_nontemporal_store(v, reinterpret_cast<u32x4*>(dst));
}
#define MFMA16(acc, a, b) (acc) = __builtin_amdgcn_mfma_f32_32x32x16_f16((a), (b), (acc), 0, 0, 0)

// C/D layout for 32x32 MFMA: col = lane&31, row = (reg&3)+8*(reg>>2)+4*(lane>>5)
__device__ inline int cd_row(int reg, int lane) {
    return (reg & 3) + 8 * (reg >> 2) + 4 * (lane >> 5);
}

// Packet layout (fp16 single-plane operands):
//   A/B-fragment packet p = tile32*16 + ks ; element = packet*64 + lane (uint4 = 8 fp16)
//   lane holds  X[tile32*32 + (lane&31)][ks*16 + (lane>>5)*8 + j]  j=0..7
// V packets: packet = gg*8 + dt (gg = flat_n/16, dt = d/32); lane holds
//   V[gg*16 + (lane>>5)*8 + j][dt*32 + (lane&31)]
// P packets (sws): packet (bloc, g16, Tm): lane holds P[Tm*32 + (lane&31)][g16*16 + hi*8 + j]
// where P = exp2(s) (unshifted; safe: s is log2-space, sigma~1.4, clamp at 15.5)
__device__ inline size_t SP(int bloc, int g16, int tm) {
    return (((size_t)bloc * NT16_ + g16) * MT32_ + tm) * 64;
}

// ---------------- P0: W -> B-operand packets (single fp16 plane) ----------------
__global__ void prep_wt(const float* __restrict__ Wq, const float* __restrict__ Wk,
                        const float* __restrict__ Wv, uint4* __restrict__ wp) {
    __shared__ unsigned short ldb[256 * 33];
    const int mat = blockIdx.x >> 3;
    const int Tc  = blockIdx.x & 7;
    const float* W = (mat == 0) ? Wq : (mat == 1) ? Wk : Wv;
    const float scl = (mat == 0) ? QS_ : 1.0f;
    const int d = threadIdx.x;
    #pragma unroll
    for (int c = 0; c < 32; c += 4) {
        const float4 v = *reinterpret_cast<const float4*>(&W[d * D_ + Tc * 32 + c]);
        ldb[d * 33 + c + 0] = f16bits(v.x * scl);
        ldb[d * 33 + c + 1] = f16bits(v.y * scl);
        ldb[d * 33 + c + 2] = f16bits(v.z * scl);
        ldb[d * 33 + c + 3] = f16bits(v.w * scl);
    }
    __syncthreads();
    const int lane = threadIdx.x & 63;
    const int pg   = threadIdx.x >> 6;
    #pragma unroll
    for (int kq = 0; kq < 4; ++kq) {
        const int ks = pg * 4 + kq;
        unsigned short hh[8];
        #pragma unroll
        for (int j = 0; j < 8; ++j)
            hh[j] = ldb[(ks * 16 + (lane >> 5) * 8 + j) * 33 + (lane & 31)];
        wp[((size_t)((mat * 8 + Tc) * 16 + ks)) * 64 + lane] = pack8(hh);
    }
}

// ---------------- P1: hr = relu(LN(|p-v| @ Wp1 + bp1)) ----------------
__global__ void prep_hr(const float* __restrict__ p_xyz, const float* __restrict__ v_xyz,
                        const float* __restrict__ Wp1, const float* __restrict__ bp1,
                        const float* __restrict__ ln_w, const float* __restrict__ ln_b,
                        float4* __restrict__ hr4) {
    const int r = blockIdx.x * 256 + threadIdx.x;
    if (r >= B_ * N_) return;
    const int b = r / N_;
    const float d0 = fabsf(p_xyz[r*3+0] - v_xyz[b*3+0]);
    const float d1 = fabsf(p_xyz[r*3+1] - v_xyz[b*3+1]);
    const float d2 = fabsf(p_xyz[r*3+2] - v_xyz[b*3+2]);
    float h[3];
    #pragma unroll
    for (int j = 0; j < 3; ++j)
        h[j] = d0*Wp1[0*3+j] + d1*Wp1[1*3+j] + d2*Wp1[2*3+j] + bp1[j];
    const float mu = (h[0]+h[1]+h[2]) * (1.0f/3.0f);
    const float e0 = h[0]-mu, e1 = h[1]-mu, e2 = h[2]-mu;
    const float var = (e0*e0 + e1*e1 + e2*e2) * (1.0f/3.0f);
    const float inv = rsqrtf(var + LN_EPS_);
    hr4[r] = make_float4(fmaxf(e0*inv*ln_w[0] + ln_b[0], 0.0f),
                         fmaxf(e1*inv*ln_w[1] + ln_b[1], 0.0f),
                         fmaxf(e2*inv*ln_w[2] + ln_b[2], 0.0f), 0.0f);
}

// ---------------- K1: projection GEMM -> fp16 packet outputs ----------------
// MODE 0: q (bias pre-scaled by QS_). MODE 1: k + pv fusion. MODE 2: v, row-scaled
// by sc[n] = 1/t0[n] (softmax denominator folded into V).
template<int MODE>
__global__ void gemm_qkv(const float* __restrict__ in,
                         const uint4* __restrict__ wp,
                         const float* __restrict__ bias,
                         const float4* __restrict__ hr4,
                         const float* __restrict__ Wp2, const float* __restrict__ bp2,
                         const float* __restrict__ sc, int roff32,
                         uint4* __restrict__ op) {
    __shared__ unsigned short tb[4][32 * 33];
    __shared__ float scb[64];
    const int tid  = threadIdx.x;
    const int lane = tid & 63;
    const int w    = tid >> 6;
    const int wr   = w & 1;
    const int wc   = w >> 1;
    const int lane31 = lane & 31;
    const int Trow = roff32 + blockIdx.x * 2 + wr;        // 32-row tile index (flat)
    const int rowA = Trow * 32 + lane31;
    const float* ap = in + (size_t)rowA * D_ + (lane >> 5) * 8;

    if (MODE == 2) {
        if (tid < 64) scb[tid] = sc[(roff32 + blockIdx.x * 2) * 32 + tid];
        __syncthreads();
    }

    f32x16 acc[4];
    #pragma unroll
    for (int t = 0; t < 4; ++t) acc[t] = (f32x16)0.0f;

    union U8 { _Float16 f[8]; f16x8 v; };
    #pragma unroll 4
    for (int ks = 0; ks < 16; ++ks) {
        const float4 f0 = *reinterpret_cast<const float4*>(ap + ks*16);
        const float4 f1 = *reinterpret_cast<const float4*>(ap + ks*16 + 4);
        const float xs[8] = {f0.x, f0.y, f0.z, f0.w, f1.x, f1.y, f1.z, f1.w};
        U8 ah, al;
        #pragma unroll
        for (int j = 0; j < 8; ++j) {
            ah.f[j] = (_Float16)xs[j];
            al.f[j] = (_Float16)(xs[j] - (float)ah.f[j]);
        }
        #pragma unroll
        for (int t = 0; t < 4; ++t) {
            const f16x8 bh = as_h8(wp[((size_t)((wc * 4 + t) * 16 + ks)) * 64 + lane]);
            MFMA16(acc[t], ah.v, bh);
            MFMA16(acc[t], al.v, bh);
        }
    }

    const float bscale = (MODE == 0) ? QS_ : 1.0f;
    float biasc[4], w0c[4], w1c[4], w2c[4], b2c[4];
    #pragma unroll
    for (int t = 0; t < 4; ++t) {
        const int cc = wc * 128 + t * 32 + lane31;
        biasc[t] = bias[cc] * bscale;
        if (MODE == 1) {
            w0c[t] = Wp2[0*D_ + cc]; w1c[t] = Wp2[1*D_ + cc];
            w2c[t] = Wp2[2*D_ + cc]; b2c[t] = bp2[cc];
        }
    }
    float4 hv[16];
    if (MODE == 1) {
        #pragma unroll
        for (int r = 0; r < 16; ++r) hv[r] = hr4[Trow * 32 + cd_row(r, lane)];
    }

    #pragma unroll
    for (int t = 0; t < 4; ++t) {
        #pragma unroll
        for (int r = 0; r < 16; ++r) {
            float v = acc[t][r] + biasc[t];
            if (MODE == 1) v += hv[r].x*w0c[t] + hv[r].y*w1c[t] + hv[r].z*w2c[t] + b2c[t];
            if (MODE == 2) v *= scb[wr * 32 + cd_row(r, lane)];   // broadcast read
            tb[w][cd_row(r, lane) * 33 + lane31] = f16bits(v);
        }
        if (MODE != 2) {
            #pragma unroll
            for (int p = 0; p < 2; ++p) {
                unsigned short hh[8];
                #pragma unroll
                for (int j = 0; j < 8; ++j)
                    hh[j] = tb[w][lane31 * 33 + p * 16 + (lane >> 5) * 8 + j];
                op[((size_t)(Trow * 16 + wc * 8 + t * 2 + p)) * 64 + lane] = pack8(hh);
            }
        } else {
            #pragma unroll
            for (int h16 = 0; h16 < 2; ++h16) {
                unsigned short hh[8];
                #pragma unroll
                for (int j = 0; j < 8; ++j)
                    hh[j] = tb[w][(h16 * 16 + (lane >> 5) * 8 + j) * 33 + lane31];
                op[((size_t)((Trow * 2 + h16) * 8 + wc * 4 + t)) * 64 + lane] = pack8(hh);
            }
        }
    }
}

// ---------------- K2: S^T GEMM -> f16 P packets + per-n column-sum partials ----
// Round-8/9 changes (targets the measured 2600 cy/tile stall, MfmaUtil 17%):
//  * qA/qB register double-buffer (col_stats-proven static-name pattern):
//    tile t+1's 16 Q loads issue BEFORE tile t's MFMA chain -> latency hidden.
//  * nontemporal P stores (via native u32x4 ext-vector; uint4 struct rejected
//    by the builtin): the 131 MB write stream no longer evicts Q/K from L2.
//  * v_cvt_pkrtz packs P pairs in 1 instr; two half-groups keep liveness low
//    (total reg budget ~252 of the 256 cap at launch_bounds(256,2)).
#define STILE(QX, TM)                                                               \
  {                                                                                 \
    f32x16 sT0 = (f32x16)0.0f, sT1 = (f32x16)0.0f;                                  \
    _Pragma("unroll")                                                               \
    for (int ks = 0; ks < 16; ks += 2) {                                            \
        MFMA16(sT0, as_h8(kf[ks]),   as_h8(QX[ks]));                                \
        MFMA16(sT1, as_h8(kf[ks+1]), as_h8(QX[ks+1]));                              \
    }                                                                               \
    unsigned int pk[4];                                                             \
    _Pragma("unroll")                                                               \
    for (int i = 0; i < 4; ++i) {                                                   \
        const float e0 = exp2f(fminf(sT0[2*i]   + sT1[2*i],   15.5f));              \
        const float e1 = exp2f(fminf(sT0[2*i+1] + sT1[2*i+1], 15.5f));              \
        tacc[2*i] += e0; tacc[2*i+1] += e1;                                         \
        pk[i] = __builtin_bit_cast(unsigned int, __builtin_amdgcn_cvt_pkrtz(e0, e1)); \
    }                                                                               \
    {                                                                               \
      const u32x2 ra = __builtin_amdgcn_permlane32_swap(pk[0], pk[2], false, false);\
      const u32x2 rb = __builtin_amdgcn_permlane32_swap(pk[1], pk[3], false, false);\
      nt_store4(ra[0], rb[0], ra[1], rb[1], &sws[SP(bl, n32 * 2 + 0, (TM)) + lane]);\
    }                                                                               \
    _Pragma("unroll")                                                               \
    for (int i = 0; i < 4; ++i) {                                                   \
        const float e0 = exp2f(fminf(sT0[2*i+8] + sT1[2*i+8], 15.5f));              \
        const float e1 = exp2f(fminf(sT0[2*i+9] + sT1[2*i+9], 15.5f));              \
        tacc[2*i+8] += e0; tacc[2*i+9] += e1;                                       \
        pk[i] = __builtin_bit_cast(unsigned int, __builtin_amdgcn_cvt_pkrtz(e0, e1)); \
    }                                                                               \
    {                                                                               \
      const u32x2 ra = __builtin_amdgcn_permlane32_swap(pk[0], pk[2], false, false);\
      const u32x2 rb = __builtin_amdgcn_permlane32_swap(pk[1], pk[3], false, false);\
      nt_store4(ra[0], rb[0], ra[1], rb[1], &sws[SP(bl, n32 * 2 + 1, (TM)) + lane]);\
    }                                                                               \
  }

template<int NB>
__global__ __launch_bounds__(256, 2)
void sgemm(const uint4* __restrict__ qp, const uint4* __restrict__ kp,
           uint4* __restrict__ sws, float* __restrict__ t0p, int b0) {
    const int tid  = threadIdx.x;
    const int lane = tid & 63;
    const int w    = tid >> 6;
    const int g    = blockIdx.x * 4 + w;
    const int mh   = g & 1;
    const int r    = g >> 1;
    const int bl   = (NB == 2) ? (r & 1) : 0;
    const int n32  = (NB == 2) ? (r >> 1) : r;
    const int b    = b0 + bl;
    const int Tn   = b * (N_ / 32) + n32;

    uint4 kf[16];
    #pragma unroll
    for (int ks = 0; ks < 16; ++ks)
        kf[ks] = kp[((size_t)(Tn * 16 + ks)) * 64 + lane];

    float tacc[16];
    #pragma unroll
    for (int q = 0; q < 16; ++q) tacc[q] = 0.0f;

    const size_t qstep = 16 * 64;                       // uint4 per m-tile
    const size_t qb0 = ((size_t)((b * MT32_ + mh * 32) * 16)) * 64 + lane;

    uint4 qA[16], qB[16];
    #pragma unroll
    for (int ks = 0; ks < 16; ++ks) qA[ks] = qp[qb0 + (size_t)ks * 64];

    for (int t2 = 0; t2 < 16; ++t2) {
        const int t = 2 * t2;
        {   // prefetch tile t+1 while tile t computes
            const size_t qbB = qb0 + (size_t)(t + 1) * qstep;
            #pragma unroll
            for (int ks = 0; ks < 16; ++ks) qB[ks] = qp[qbB + (size_t)ks * 64];
        }
        STILE(qA, mh * 32 + t);
        if (t2 < 15) {   // prefetch tile t+2 while tile t+1 computes
            const size_t qbA = qb0 + (size_t)(t + 2) * qstep;
            #pragma unroll
            for (int ks = 0; ks < 16; ++ks) qA[ks] = qp[qbA + (size_t)ks * 64];
        }
        STILE(qB, mh * 32 + t + 1);
    }

    // column-sum partials: reduce over the 32 m-lanes (within each hi half)
    #pragma unroll
    for (int q = 0; q < 16; ++q) {
        #pragma unroll
        for (int off = 16; off; off >>= 1)
            tacc[q] += __shfl_xor(tacc[q], off, 64);
    }
    if ((lane & 31) == 0) {
        #pragma unroll
        for (int q = 0; q < 16; ++q) {
            const int n = n32 * 32 + cd_row(q, lane);
            t0p[((size_t)(mh * B_ + b)) * N_ + n] = tacc[q];
        }
    }
}
#undef STILE

// ---------------- K3: sc[n] = 1/t0[n] (softmax denom; shift cancels exactly) ----
__global__ void calc_sc(const float* __restrict__ t0p, float* __restrict__ sc, int b0) {
    const int b   = b0 + (blockIdx.x >> 4);
    const int sl  = blockIdx.x & 15;
    const int tid = threadIdx.x;
    constexpr int CH = N_ / 4 / 16;               // float4 per slice
    const float4* p0 = (const float4*)(t0p + ((size_t)(0 * B_ + b)) * N_) + sl * CH;
    const float4* p1 = (const float4*)(t0p + ((size_t)(1 * B_ + b)) * N_) + sl * CH;
    float4* s4 = (float4*)(sc + (size_t)b * N_) + sl * CH;
    for (int i = tid; i < CH; i += 256) {
        const float4 a = p0[i], c = p1[i];
        float4 o;
        o.x = fminf(1.0f / (a.x + c.x), 60000.0f);   // clamp: keep V*sc f16-finite
        o.y = fminf(1.0f / (a.y + c.y), 60000.0f);
        o.z = fminf(1.0f / (a.z + c.z), 60000.0f);
        o.w = fminf(1.0f / (a.w + c.w), 60000.0f);
        s4[i] = o;
    }
}

// ---------------- K4: attention PV from stored P -- pure stream + MFMA ----
// Round-7 proven (plain stores, one writer per (ns,b,mt) region, no barriers).
template<int NB>
__global__ __launch_bounds__(256, 3)
void attn_out(const uint4* __restrict__ sws, const uint4* __restrict__ vp,
              float* __restrict__ part, int b0) {
    const int tid  = threadIdx.x;
    const int lane = tid & 63;
    const int w    = tid >> 6;        // 0..3
    const int wm   = w & 1;           // m 32-subtile
    const int wd   = w >> 1;          // d-half
    const int lane31 = lane & 31;

    const int bid  = blockIdx.x;
    const int low3 = bid & 7;         // XCD pinning
    const int rest = bid >> 3;
    const int g    = (rest & (2*NB - 1)) * 8 + low3;   // 0..16*NB-1
    const int bl   = g >> 4;                           // 0 for NB=1
    const int b    = b0 + bl;
    const int ns   = g & 15;
    const int mt   = rest >> (NB == 2 ? 2 : 1);        // 0..31
    const int m0   = mt * 64;
    const int TmG  = mt * 2 + wm;

    f32x16 oacc[4];
    #pragma unroll
    for (int t = 0; t < 4; ++t) oacc[t] = (f32x16)0.0f;

    #pragma unroll 2
    for (int c = 0; c < NPB_ / 64; ++c) {              // 16 chunks of 64 n
        const int nbase = ns * NPB_ + c * 64;
        const int g16   = nbase >> 4;
        uint4 af[4];
        #pragma unroll
        for (int t = 0; t < 4; ++t)
            af[t] = sws[SP(bl, g16 + t, TmG) + lane];
        const size_t gg0 = (size_t)((b * N_ + nbase) >> 4);
        #pragma unroll
        for (int k2 = 0; k2 < 4; ++k2) {
            #pragma unroll
            for (int dt = 0; dt < 4; ++dt) {
                MFMA16(oacc[dt], as_h8(af[k2]),
                       as_h8(vp[((gg0 + k2) * 8 + wd * 4 + dt) * 64 + lane]));
            }
        }
    }
    // one writer per (ns, b, mt) region -> plain coalesced stores, no atomics
    float* pb = part + (size_t)ns * OUTSZ_;
    #pragma unroll
    for (int dt = 0; dt < 4; ++dt) {
        #pragma unroll
        for (int r = 0; r < 16; ++r) {
            const int row = m0 + wm * 32 + cd_row(r, lane);
            pb[((size_t)(b * M_ + row)) * D_ + wd * 128 + dt * 32 + lane31] = oacc[dt][r];
        }
    }
}

// ---------------- K5: out = v_features + sum(parts) ----------------
__global__ void reduce_out(const float4* __restrict__ v, const float4* __restrict__ part,
                           float4* __restrict__ out) {
    const size_t i = (size_t)blockIdx.x * 256 + threadIdx.x;
    float4 a = v[i];
    #pragma unroll
    for (int c = 0; c < NCOPY_; ++c) {
        const float4 p = part[(size_t)c * (OUTSZ_ / 4) + i];
        a.x += p.x; a.y += p.y; a.z += p.z; a.w += p.w;
    }
    out[i] = a;
}

} // anonymous namespace

extern "C" void kernel_launch(void* const* d_in, const int* in_sizes, int n_in,
                              void* d_out, int out_size, void* d_ws, size_t ws_size,
                              hipStream_t stream) {
    const float* p_xyz      = (const float*)d_in[0];
    const float* v_xyz      = (const float*)d_in[1];
    const float* p_features = (const float*)d_in[2];
    const float* v_features = (const float*)d_in[3];
    const float* Wq  = (const float*)d_in[4];
    const float* bq  = (const float*)d_in[5];
    const float* Wk  = (const float*)d_in[6];
    const float* bk  = (const float*)d_in[7];
    const float* Wv  = (const float*)d_in[8];
    const float* bv  = (const float*)d_in[9];
    const float* Wp1 = (const float*)d_in[10];
    const float* bp1 = (const float*)d_in[11];
    const float* lnw = (const float*)d_in[12];
    const float* lnb = (const float*)d_in[13];
    const float* Wp2 = (const float*)d_in[14];
    const float* bp2 = (const float*)d_in[15];
    float* out = (float*)d_out;

    // ---- workspace carve-up (256B aligned) ----
    char* p = (char*)d_ws;
    auto alloc = [&](size_t bytes) {
        void* r = (void*)p;
        p += (bytes + 255) & ~(size_t)255;
        return r;
    };
    uint4* qpk = (uint4*)alloc((size_t)B_*M_*D_*2);   // fp16 packets
    uint4* kpk = (uint4*)alloc((size_t)B_*N_*D_*2);
    uint4* vpk = (uint4*)alloc((size_t)B_*N_*D_*2);
    uint4* wp  = (uint4*)alloc((size_t)3*D_*D_*2);
    float4* hr4 = (float4*)alloc((size_t)B_*N_*16);
    float*  t0p = (float*)alloc((size_t)2*B_*N_*4);   // column-sum partials [2][B][N]
    float*  sc  = (float*)alloc((size_t)B_*N_*4);
    float*  part = (float*)alloc((size_t)NCOPY_*OUTSZ_*4);   // 64 MiB

    const size_t swsFull = (size_t)B_ * M_ * N_ * 2;         // 134 MB (P packets)
    const size_t used = (size_t)(p - (char*)d_ws);
    const bool full = ws_size >= used + swsFull;
    uint4* sws = (uint4*)alloc(full ? swsFull : swsFull / 2);

    constexpr size_t WMAT = (size_t)D_*D_/8;   // uint4 per weight matrix

    prep_wt<<<3*8, 256, 0, stream>>>(Wq, Wk, Wv, wp);
    prep_hr<<<(B_*N_)/256, 256, 0, stream>>>(p_xyz, v_xyz, Wp1, bp1, lnw, lnb, hr4);

    gemm_qkv<0><<<(B_*M_)/64, 256, 0, stream>>>(v_features, wp + 0*WMAT, bq, hr4, Wp2, bp2, nullptr, 0, qpk);
    gemm_qkv<1><<<(B_*N_)/64, 256, 0, stream>>>(p_features, wp + 1*WMAT, bk, hr4, Wp2, bp2, nullptr, 0, kpk);

    if (full) {
        sgemm<2><<<512, 256, 0, stream>>>(qpk, kpk, sws, t0p, 0);
        calc_sc<<<2*16, 256, 0, stream>>>(t0p, sc, 0);
        gemm_qkv<2><<<(B_*N_)/64, 256, 0, stream>>>(p_features, wp + 2*WMAT, bv, hr4, Wp2, bp2, sc, 0, vpk);
        attn_out<2><<<8*4*32, 256, 0, stream>>>(sws, vpk, part, 0);
    } else {
        for (int b = 0; b < B_; ++b) {
            sgemm<1><<<256, 256, 0, stream>>>(qpk, kpk, sws, t0p, b);
            calc_sc<<<16, 256, 0, stream>>>(t0p, sc, b);
            gemm_qkv<2><<<N_/64, 256, 0, stream>>>(p_features, wp + 2*WMAT, bv, hr4, Wp2, bp2, sc,
                                                   b * (N_/32), vpk);
            attn_out<1><<<8*2*32, 256, 0, stream>>>(sws, vpk, part, b);
        }
    }
    reduce_out<<<(OUTSZ_/4)/256, 256, 0, stream>>>((const float4*)v_features,
                                                   (const float4*)part, (float4*)out);
}

// Round 10
// 322.750 us; speedup vs baseline: 1.0589x; 1.0589x over previous
//
#include <hip/hip_runtime.h>
#include <math.h>

namespace {

constexpr int   B_ = 2;
constexpr int   N_ = 16384;
constexpr int   M_ = 2048;
constexpr int   D_ = 256;
constexpr float QS_ = 0.09016844005556021f;  // (1/sqrt(256)) * log2(e), folded into Wq/bq
constexpr float LN_EPS_ = 1e-5f;
constexpr int   NS_  = 16;                   // n-splits in attn_out
constexpr int   NPB_ = N_ / NS_;             // 1024 n per block
constexpr int   NCOPY_ = 16;                 // one part copy per ns -> plain stores
constexpr int   NT16_ = N_ / 16;             // 1024 n16-groups per batch
constexpr int   MT32_ = M_ / 32;             // 64 m-tiles per batch
constexpr size_t OUTSZ_ = (size_t)B_*M_*D_;

typedef _Float16 f16x8 __attribute__((ext_vector_type(8)));
typedef float    f32x16 __attribute__((ext_vector_type(16)));
typedef unsigned int u32x2 __attribute__((ext_vector_type(2)));
typedef unsigned int u32x4 __attribute__((ext_vector_type(4)));   // native vec for nontemporal

__device__ inline f16x8 as_h8(uint4 u) { return __builtin_bit_cast(f16x8, u); }
__device__ inline unsigned short f16bits(float x) {
    return __builtin_bit_cast(unsigned short, (_Float16)x);
}
__device__ inline uint4 pack8(const unsigned short v[8]) {
    return make_uint4((uint32_t)v[0] | ((uint32_t)v[1] << 16),
                      (uint32_t)v[2] | ((uint32_t)v[3] << 16),
                      (uint32_t)v[4] | ((uint32_t)v[5] << 16),
                      (uint32_t)v[6] | ((uint32_t)v[7] << 16));
}
__device__ inline void nt_store4(unsigned int a, unsigned int b,
                                 unsigned int c, unsigned int d, uint4* dst) {
    u32x4 v; v[0] = a; v[1] = b; v[2] = c; v[3] = d;
    __builtin_nontemporal_store(v, reinterpret_cast<u32x4*>(dst));
}
#define MFMA16(acc, a, b) (acc) = __builtin_amdgcn_mfma_f32_32x32x16_f16((a), (b), (acc), 0, 0, 0)

// C/D layout for 32x32 MFMA: col = lane&31, row = (reg&3)+8*(reg>>2)+4*(lane>>5)
__device__ inline int cd_row(int reg, int lane) {
    return (reg & 3) + 8 * (reg >> 2) + 4 * (lane >> 5);
}

// Packet layout (fp16 single-plane operands):
//   A/B-fragment packet p = tile32*16 + ks ; element = packet*64 + lane (uint4 = 8 fp16)
//   lane holds  X[tile32*32 + (lane&31)][ks*16 + (lane>>5)*8 + j]  j=0..7
// V packets: packet = gg*8 + dt (gg = flat_n/16, dt = d/32); lane holds
//   V[gg*16 + (lane>>5)*8 + j][dt*32 + (lane&31)]
// P packets (sws): packet (bloc, g16, Tm): lane holds P[Tm*32 + (lane&31)][g16*16 + hi*8 + j]
// where P = exp2(s) (unshifted; safe: s is log2-space, sigma~1.4, clamp at 15.5)
__device__ inline size_t SP(int bloc, int g16, int tm) {
    return (((size_t)bloc * NT16_ + g16) * MT32_ + tm) * 64;
}

// ---------------- P0: W -> B-operand packets (single fp16 plane) ----------------
__global__ void prep_wt(const float* __restrict__ Wq, const float* __restrict__ Wk,
                        const float* __restrict__ Wv, uint4* __restrict__ wp) {
    __shared__ unsigned short ldb[256 * 33];
    const int mat = blockIdx.x >> 3;
    const int Tc  = blockIdx.x & 7;
    const float* W = (mat == 0) ? Wq : (mat == 1) ? Wk : Wv;
    const float scl = (mat == 0) ? QS_ : 1.0f;
    const int d = threadIdx.x;
    #pragma unroll
    for (int c = 0; c < 32; c += 4) {
        const float4 v = *reinterpret_cast<const float4*>(&W[d * D_ + Tc * 32 + c]);
        ldb[d * 33 + c + 0] = f16bits(v.x * scl);
        ldb[d * 33 + c + 1] = f16bits(v.y * scl);
        ldb[d * 33 + c + 2] = f16bits(v.z * scl);
        ldb[d * 33 + c + 3] = f16bits(v.w * scl);
    }
    __syncthreads();
    const int lane = threadIdx.x & 63;
    const int pg   = threadIdx.x >> 6;
    #pragma unroll
    for (int kq = 0; kq < 4; ++kq) {
        const int ks = pg * 4 + kq;
        unsigned short hh[8];
        #pragma unroll
        for (int j = 0; j < 8; ++j)
            hh[j] = ldb[(ks * 16 + (lane >> 5) * 8 + j) * 33 + (lane & 31)];
        wp[((size_t)((mat * 8 + Tc) * 16 + ks)) * 64 + lane] = pack8(hh);
    }
}

// ---------------- P1: hr = relu(LN(|p-v| @ Wp1 + bp1)) ----------------
__global__ void prep_hr(const float* __restrict__ p_xyz, const float* __restrict__ v_xyz,
                        const float* __restrict__ Wp1, const float* __restrict__ bp1,
                        const float* __restrict__ ln_w, const float* __restrict__ ln_b,
                        float4* __restrict__ hr4) {
    const int r = blockIdx.x * 256 + threadIdx.x;
    if (r >= B_ * N_) return;
    const int b = r / N_;
    const float d0 = fabsf(p_xyz[r*3+0] - v_xyz[b*3+0]);
    const float d1 = fabsf(p_xyz[r*3+1] - v_xyz[b*3+1]);
    const float d2 = fabsf(p_xyz[r*3+2] - v_xyz[b*3+2]);
    float h[3];
    #pragma unroll
    for (int j = 0; j < 3; ++j)
        h[j] = d0*Wp1[0*3+j] + d1*Wp1[1*3+j] + d2*Wp1[2*3+j] + bp1[j];
    const float mu = (h[0]+h[1]+h[2]) * (1.0f/3.0f);
    const float e0 = h[0]-mu, e1 = h[1]-mu, e2 = h[2]-mu;
    const float var = (e0*e0 + e1*e1 + e2*e2) * (1.0f/3.0f);
    const float inv = rsqrtf(var + LN_EPS_);
    hr4[r] = make_float4(fmaxf(e0*inv*ln_w[0] + ln_b[0], 0.0f),
                         fmaxf(e1*inv*ln_w[1] + ln_b[1], 0.0f),
                         fmaxf(e2*inv*ln_w[2] + ln_b[2], 0.0f), 0.0f);
}

// ---------------- K1: projection GEMM -> fp16 packet outputs ----------------
// MODE 0: q (bias pre-scaled by QS_). MODE 1: k + pv fusion. MODE 2: v, row-scaled
// by sc[n] = 1/t0[n] (softmax denominator folded into V).
template<int MODE>
__global__ void gemm_qkv(const float* __restrict__ in,
                         const uint4* __restrict__ wp,
                         const float* __restrict__ bias,
                         const float4* __restrict__ hr4,
                         const float* __restrict__ Wp2, const float* __restrict__ bp2,
                         const float* __restrict__ sc, int roff32,
                         uint4* __restrict__ op) {
    __shared__ unsigned short tb[4][32 * 33];
    __shared__ float scb[64];
    const int tid  = threadIdx.x;
    const int lane = tid & 63;
    const int w    = tid >> 6;
    const int wr   = w & 1;
    const int wc   = w >> 1;
    const int lane31 = lane & 31;
    const int Trow = roff32 + blockIdx.x * 2 + wr;        // 32-row tile index (flat)
    const int rowA = Trow * 32 + lane31;
    const float* ap = in + (size_t)rowA * D_ + (lane >> 5) * 8;

    if (MODE == 2) {
        if (tid < 64) scb[tid] = sc[(roff32 + blockIdx.x * 2) * 32 + tid];
        __syncthreads();
    }

    f32x16 acc[4];
    #pragma unroll
    for (int t = 0; t < 4; ++t) acc[t] = (f32x16)0.0f;

    union U8 { _Float16 f[8]; f16x8 v; };
    #pragma unroll 4
    for (int ks = 0; ks < 16; ++ks) {
        const float4 f0 = *reinterpret_cast<const float4*>(ap + ks*16);
        const float4 f1 = *reinterpret_cast<const float4*>(ap + ks*16 + 4);
        const float xs[8] = {f0.x, f0.y, f0.z, f0.w, f1.x, f1.y, f1.z, f1.w};
        U8 ah, al;
        #pragma unroll
        for (int j = 0; j < 8; ++j) {
            ah.f[j] = (_Float16)xs[j];
            al.f[j] = (_Float16)(xs[j] - (float)ah.f[j]);
        }
        #pragma unroll
        for (int t = 0; t < 4; ++t) {
            const f16x8 bh = as_h8(wp[((size_t)((wc * 4 + t) * 16 + ks)) * 64 + lane]);
            MFMA16(acc[t], ah.v, bh);
            MFMA16(acc[t], al.v, bh);
        }
    }

    const float bscale = (MODE == 0) ? QS_ : 1.0f;
    float biasc[4], w0c[4], w1c[4], w2c[4], b2c[4];
    #pragma unroll
    for (int t = 0; t < 4; ++t) {
        const int cc = wc * 128 + t * 32 + lane31;
        biasc[t] = bias[cc] * bscale;
        if (MODE == 1) {
            w0c[t] = Wp2[0*D_ + cc]; w1c[t] = Wp2[1*D_ + cc];
            w2c[t] = Wp2[2*D_ + cc]; b2c[t] = bp2[cc];
        }
    }
    float4 hv[16];
    if (MODE == 1) {
        #pragma unroll
        for (int r = 0; r < 16; ++r) hv[r] = hr4[Trow * 32 + cd_row(r, lane)];
    }

    #pragma unroll
    for (int t = 0; t < 4; ++t) {
        #pragma unroll
        for (int r = 0; r < 16; ++r) {
            float v = acc[t][r] + biasc[t];
            if (MODE == 1) v += hv[r].x*w0c[t] + hv[r].y*w1c[t] + hv[r].z*w2c[t] + b2c[t];
            if (MODE == 2) v *= scb[wr * 32 + cd_row(r, lane)];   // broadcast read
            tb[w][cd_row(r, lane) * 33 + lane31] = f16bits(v);
        }
        if (MODE != 2) {
            #pragma unroll
            for (int p = 0; p < 2; ++p) {
                unsigned short hh[8];
                #pragma unroll
                for (int j = 0; j < 8; ++j)
                    hh[j] = tb[w][lane31 * 33 + p * 16 + (lane >> 5) * 8 + j];
                op[((size_t)(Trow * 16 + wc * 8 + t * 2 + p)) * 64 + lane] = pack8(hh);
            }
        } else {
            #pragma unroll
            for (int h16 = 0; h16 < 2; ++h16) {
                unsigned short hh[8];
                #pragma unroll
                for (int j = 0; j < 8; ++j)
                    hh[j] = tb[w][(h16 * 16 + (lane >> 5) * 8 + j) * 33 + lane31];
                op[((size_t)((Trow * 2 + h16) * 8 + wc * 4 + t)) * 64 + lane] = pack8(hh);
            }
        }
    }
}

// ---------------- K2: S^T GEMM -> f16 P packets + per-n column-sum partials ----
// Round-10: registers-slim (round-7 proven, no spill) + TLP. Round-9's qA/qB
// double-buffer spilled (VGPR pinned 128, FETCH +32MB scratch, 179us cold
// dispatch = scratch alloc). Fixes:
//  * single qa buffer, WAR-reuse prefetch: tile t+1's loads issue right after
//    tile t's MFMAs (HW scoreboard safe), latency hides under exp/pack/store.
//  * m split 4-way (mq): grid 512 -> 1024 blocks; round-7 was GRID-limited at
//    2 blocks/CU while ~168 unified regs/wave allow 3 waves/SIMD -> +50% TLP.
//  * nontemporal P stores: write stream doesn't evict Q/K from L2.
template<int NB>
__global__ __launch_bounds__(256, 2)
void sgemm(const uint4* __restrict__ qp, const uint4* __restrict__ kp,
           uint4* __restrict__ sws, float* __restrict__ t0p, int b0) {
    const int tid  = threadIdx.x;
    const int lane = tid & 63;
    const int w    = tid >> 6;
    const int g    = blockIdx.x * 4 + w;
    const int mq   = g & 3;                  // m quarter: 16 tiles
    const int r    = g >> 2;
    const int bl   = (NB == 2) ? (r & 1) : 0;
    const int n32  = (NB == 2) ? (r >> 1) : r;
    const int b    = b0 + bl;
    const int Tn   = b * (N_ / 32) + n32;

    uint4 kf[16];
    #pragma unroll
    for (int ks = 0; ks < 16; ++ks)
        kf[ks] = kp[((size_t)(Tn * 16 + ks)) * 64 + lane];

    float tacc[16];
    #pragma unroll
    for (int q = 0; q < 16; ++q) tacc[q] = 0.0f;

    const size_t qstep = 16 * 64;                       // uint4 per m-tile
    const size_t qb0 = ((size_t)((b * MT32_ + mq * 16) * 16)) * 64 + lane;

    uint4 qa[16];
    #pragma unroll
    for (int ks = 0; ks < 16; ++ks) qa[ks] = qp[qb0 + (size_t)ks * 64];

    for (int t = 0; t < 16; ++t) {
        f32x16 sT0 = (f32x16)0.0f, sT1 = (f32x16)0.0f;
        #pragma unroll
        for (int ks = 0; ks < 16; ks += 2) {
            MFMA16(sT0, as_h8(kf[ks]),   as_h8(qa[ks]));
            MFMA16(sT1, as_h8(kf[ks+1]), as_h8(qa[ks+1]));
        }
        // WAR-reuse prefetch: reload qa with tile t+1 now; MFMAs read operands
        // at issue, so overwriting is scoreboard-safe; load latency overlaps
        // the exp/pack/store tail below (no extra registers).
        if (t < 15) {
            const size_t qb = qb0 + (size_t)(t + 1) * qstep;
            #pragma unroll
            for (int ks = 0; ks < 16; ++ks) qa[ks] = qp[qb + (size_t)ks * 64];
        }
        const int Tm = mq * 16 + t;
        unsigned int pk[4];
        #pragma unroll
        for (int i = 0; i < 4; ++i) {
            const float e0 = exp2f(fminf(sT0[2*i]   + sT1[2*i],   15.5f));
            const float e1 = exp2f(fminf(sT0[2*i+1] + sT1[2*i+1], 15.5f));
            tacc[2*i] += e0; tacc[2*i+1] += e1;
            pk[i] = __builtin_bit_cast(unsigned int, __builtin_amdgcn_cvt_pkrtz(e0, e1));
        }
        {
            const u32x2 ra = __builtin_amdgcn_permlane32_swap(pk[0], pk[2], false, false);
            const u32x2 rb = __builtin_amdgcn_permlane32_swap(pk[1], pk[3], false, false);
            nt_store4(ra[0], rb[0], ra[1], rb[1], &sws[SP(bl, n32 * 2 + 0, Tm) + lane]);
        }
        #pragma unroll
        for (int i = 0; i < 4; ++i) {
            const float e0 = exp2f(fminf(sT0[2*i+8] + sT1[2*i+8], 15.5f));
            const float e1 = exp2f(fminf(sT0[2*i+9] + sT1[2*i+9], 15.5f));
            tacc[2*i+8] += e0; tacc[2*i+9] += e1;
            pk[i] = __builtin_bit_cast(unsigned int, __builtin_amdgcn_cvt_pkrtz(e0, e1));
        }
        {
            const u32x2 ra = __builtin_amdgcn_permlane32_swap(pk[0], pk[2], false, false);
            const u32x2 rb = __builtin_amdgcn_permlane32_swap(pk[1], pk[3], false, false);
            nt_store4(ra[0], rb[0], ra[1], rb[1], &sws[SP(bl, n32 * 2 + 1, Tm) + lane]);
        }
    }

    // column-sum quarter-partials: reduce over the 32 m-lanes (per hi half)
    #pragma unroll
    for (int q = 0; q < 16; ++q) {
        #pragma unroll
        for (int off = 16; off; off >>= 1)
            tacc[q] += __shfl_xor(tacc[q], off, 64);
    }
    if ((lane & 31) == 0) {
        #pragma unroll
        for (int q = 0; q < 16; ++q) {
            const int n = n32 * 32 + cd_row(q, lane);
            t0p[((size_t)(mq * B_ + b)) * N_ + n] = tacc[q];
        }
    }
}

// ---------------- K3: sc[n] = 1/t0[n] (softmax denom; shift cancels exactly) ----
__global__ void calc_sc(const float* __restrict__ t0p, float* __restrict__ sc, int b0) {
    const int b   = b0 + (blockIdx.x >> 4);
    const int sl  = blockIdx.x & 15;
    const int tid = threadIdx.x;
    constexpr int CH = N_ / 4 / 16;               // float4 per slice
    const float4* p0 = (const float4*)(t0p + ((size_t)(0 * B_ + b)) * N_) + sl * CH;
    const float4* p1 = (const float4*)(t0p + ((size_t)(1 * B_ + b)) * N_) + sl * CH;
    const float4* p2 = (const float4*)(t0p + ((size_t)(2 * B_ + b)) * N_) + sl * CH;
    const float4* p3 = (const float4*)(t0p + ((size_t)(3 * B_ + b)) * N_) + sl * CH;
    float4* s4 = (float4*)(sc + (size_t)b * N_) + sl * CH;
    for (int i = tid; i < CH; i += 256) {
        const float4 a = p0[i], c = p1[i], d = p2[i], e = p3[i];
        float4 o;
        o.x = fminf(1.0f / (a.x + c.x + d.x + e.x), 60000.0f);   // keep V*sc f16-finite
        o.y = fminf(1.0f / (a.y + c.y + d.y + e.y), 60000.0f);
        o.z = fminf(1.0f / (a.z + c.z + d.z + e.z), 60000.0f);
        o.w = fminf(1.0f / (a.w + c.w + d.w + e.w), 60000.0f);
        s4[i] = o;
    }
}

// ---------------- K4: attention PV from stored P -- pure stream + MFMA ----
// Round-7 proven (plain stores, one writer per (ns,b,mt) region, no barriers).
template<int NB>
__global__ __launch_bounds__(256, 3)
void attn_out(const uint4* __restrict__ sws, const uint4* __restrict__ vp,
              float* __restrict__ part, int b0) {
    const int tid  = threadIdx.x;
    const int lane = tid & 63;
    const int w    = tid >> 6;        // 0..3
    const int wm   = w & 1;           // m 32-subtile
    const int wd   = w >> 1;          // d-half
    const int lane31 = lane & 31;

    const int bid  = blockIdx.x;
    const int low3 = bid & 7;         // XCD pinning
    const int rest = bid >> 3;
    const int g    = (rest & (2*NB - 1)) * 8 + low3;   // 0..16*NB-1
    const int bl   = g >> 4;                           // 0 for NB=1
    const int b    = b0 + bl;
    const int ns   = g & 15;
    const int mt   = rest >> (NB == 2 ? 2 : 1);        // 0..31
    const int m0   = mt * 64;
    const int TmG  = mt * 2 + wm;

    f32x16 oacc[4];
    #pragma unroll
    for (int t = 0; t < 4; ++t) oacc[t] = (f32x16)0.0f;

    #pragma unroll 2
    for (int c = 0; c < NPB_ / 64; ++c) {              // 16 chunks of 64 n
        const int nbase = ns * NPB_ + c * 64;
        const int g16   = nbase >> 4;
        uint4 af[4];
        #pragma unroll
        for (int t = 0; t < 4; ++t)
            af[t] = sws[SP(bl, g16 + t, TmG) + lane];
        const size_t gg0 = (size_t)((b * N_ + nbase) >> 4);
        #pragma unroll
        for (int k2 = 0; k2 < 4; ++k2) {
            #pragma unroll
            for (int dt = 0; dt < 4; ++dt) {
                MFMA16(oacc[dt], as_h8(af[k2]),
                       as_h8(vp[((gg0 + k2) * 8 + wd * 4 + dt) * 64 + lane]));
            }
        }
    }
    // one writer per (ns, b, mt) region -> plain coalesced stores, no atomics
    float* pb = part + (size_t)ns * OUTSZ_;
    #pragma unroll
    for (int dt = 0; dt < 4; ++dt) {
        #pragma unroll
        for (int r = 0; r < 16; ++r) {
            const int row = m0 + wm * 32 + cd_row(r, lane);
            pb[((size_t)(b * M_ + row)) * D_ + wd * 128 + dt * 32 + lane31] = oacc[dt][r];
        }
    }
}

// ---------------- K5: out = v_features + sum(parts) ----------------
__global__ void reduce_out(const float4* __restrict__ v, const float4* __restrict__ part,
                           float4* __restrict__ out) {
    const size_t i = (size_t)blockIdx.x * 256 + threadIdx.x;
    float4 a = v[i];
    #pragma unroll
    for (int c = 0; c < NCOPY_; ++c) {
        const float4 p = part[(size_t)c * (OUTSZ_ / 4) + i];
        a.x += p.x; a.y += p.y; a.z += p.z; a.w += p.w;
    }
    out[i] = a;
}

} // anonymous namespace

extern "C" void kernel_launch(void* const* d_in, const int* in_sizes, int n_in,
                              void* d_out, int out_size, void* d_ws, size_t ws_size,
                              hipStream_t stream) {
    const float* p_xyz      = (const float*)d_in[0];
    const float* v_xyz      = (const float*)d_in[1];
    const float* p_features = (const float*)d_in[2];
    const float* v_features = (const float*)d_in[3];
    const float* Wq  = (const float*)d_in[4];
    const float* bq  = (const float*)d_in[5];
    const float* Wk  = (const float*)d_in[6];
    const float* bk  = (const float*)d_in[7];
    const float* Wv  = (const float*)d_in[8];
    const float* bv  = (const float*)d_in[9];
    const float* Wp1 = (const float*)d_in[10];
    const float* bp1 = (const float*)d_in[11];
    const float* lnw = (const float*)d_in[12];
    const float* lnb = (const float*)d_in[13];
    const float* Wp2 = (const float*)d_in[14];
    const float* bp2 = (const float*)d_in[15];
    float* out = (float*)d_out;

    // ---- workspace carve-up (256B aligned) ----
    char* p = (char*)d_ws;
    auto alloc = [&](size_t bytes) {
        void* r = (void*)p;
        p += (bytes + 255) & ~(size_t)255;
        return r;
    };
    uint4* qpk = (uint4*)alloc((size_t)B_*M_*D_*2);   // fp16 packets
    uint4* kpk = (uint4*)alloc((size_t)B_*N_*D_*2);
    uint4* vpk = (uint4*)alloc((size_t)B_*N_*D_*2);
    uint4* wp  = (uint4*)alloc((size_t)3*D_*D_*2);
    float4* hr4 = (float4*)alloc((size_t)B_*N_*16);
    float*  t0p = (float*)alloc((size_t)4*B_*N_*4);   // column-sum quarters [4][B][N]
    float*  sc  = (float*)alloc((size_t)B_*N_*4);
    float*  part = (float*)alloc((size_t)NCOPY_*OUTSZ_*4);   // 64 MiB

    const size_t swsFull = (size_t)B_ * M_ * N_ * 2;         // 134 MB (P packets)
    const size_t used = (size_t)(p - (char*)d_ws);
    const bool full = ws_size >= used + swsFull;
    uint4* sws = (uint4*)alloc(full ? swsFull : swsFull / 2);

    constexpr size_t WMAT = (size_t)D_*D_/8;   // uint4 per weight matrix

    prep_wt<<<3*8, 256, 0, stream>>>(Wq, Wk, Wv, wp);
    prep_hr<<<(B_*N_)/256, 256, 0, stream>>>(p_xyz, v_xyz, Wp1, bp1, lnw, lnb, hr4);

    gemm_qkv<0><<<(B_*M_)/64, 256, 0, stream>>>(v_features, wp + 0*WMAT, bq, hr4, Wp2, bp2, nullptr, 0, qpk);
    gemm_qkv<1><<<(B_*N_)/64, 256, 0, stream>>>(p_features, wp + 1*WMAT, bk, hr4, Wp2, bp2, nullptr, 0, kpk);

    if (full) {
        sgemm<2><<<1024, 256, 0, stream>>>(qpk, kpk, sws, t0p, 0);
        calc_sc<<<2*16, 256, 0, stream>>>(t0p, sc, 0);
        gemm_qkv<2><<<(B_*N_)/64, 256, 0, stream>>>(p_features, wp + 2*WMAT, bv, hr4, Wp2, bp2, sc, 0, vpk);
        attn_out<2><<<8*4*32, 256, 0, stream>>>(sws, vpk, part, 0);
    } else {
        for (int b = 0; b < B_; ++b) {
            sgemm<1><<<512, 256, 0, stream>>>(qpk, kpk, sws, t0p, b);
            calc_sc<<<16, 256, 0, stream>>>(t0p, sc, b);
            gemm_qkv<2><<<N_/64, 256, 0, stream>>>(p_features, wp + 2*WMAT, bv, hr4, Wp2, bp2, sc,
                                                   b * (N_/32), vpk);
            attn_out<1><<<8*2*32, 256, 0, stream>>>(sws, vpk, part, b);
        }
    }
    reduce_out<<<(OUTSZ_/4)/256, 256, 0, stream>>>((const float4*)v_features,
                                                   (const float4*)part, (float4*)out);
}